// Round 1
// baseline (281.543 us; speedup 1.0000x reference)
//
#include <hip/hip_runtime.h>
#include <math.h>
#include <stdint.h>

#define B_ 4
#define N_ 250000
#define P_ 1000
#define G_ 32
#define C_ 81
#define RPN_BATCH 256
#define ROI_BATCH 128

#define APT 4                         // anchors per thread in rpn_assign
#define BK1 256
#define ANCH_PER_BLK (BK1 * APT)      // 1024
#define NB1 ((N_ + ANCH_PER_BLK - 1) / ANCH_PER_BLK)   // 245
#define BK3 256
#define NB3 ((N_ + BK3 - 1) / BK3)    // 977

__device__ __forceinline__ float iou_one(float a0, float a1, float a2, float a3,
                                         float areaA,
                                         float b0, float b1, float b2, float b3) {
    float ltx = fmaxf(a0, b0), lty = fmaxf(a1, b1);
    float rbx = fminf(a2, b2), rby = fminf(a3, b3);
    float w = fmaxf(rbx - ltx, 0.f), h = fmaxf(rby - lty, 0.f);
    float inter = w * h;
    float areaB = (b2 - b0) * (b3 - b1);
    return inter / (areaA + areaB - inter + 1e-6f);
}

__device__ __forceinline__ unsigned long long shfl_xor_u64(unsigned long long v, int m) {
    unsigned lo = (unsigned)v, hi = (unsigned)(v >> 32);
    lo = __shfl_xor(lo, m);
    hi = __shfl_xor(hi, m);
    return ((unsigned long long)hi << 32) | lo;
}

__device__ __forceinline__ float smooth_l1(float x) {
    float ax = fabsf(x);
    return (ax < 1.f) ? 0.5f * x * x : ax - 0.5f;
}

// Kernel 1: per-anchor labels (thresholds on max_iou) + per-block per-gt best anchor.
__global__ void __launch_bounds__(BK1) rpn_assign(
        const float* __restrict__ anchors, const float* __restrict__ gt_boxes,
        int8_t* __restrict__ labels, unsigned long long* __restrict__ blockBest) {
    __shared__ float sgt[G_ * 4];
    __shared__ unsigned long long swb[BK1 / 64][G_];
    int b = blockIdx.y;
    int tid = threadIdx.x;
    if (tid < G_ * 4) sgt[tid] = gt_boxes[b * G_ * 4 + tid];
    __syncthreads();

    unsigned long long best[G_];
#pragma unroll
    for (int g = 0; g < G_; ++g) best[g] = 0ull;

    int base = blockIdx.x * ANCH_PER_BLK;
    for (int k = 0; k < APT; ++k) {
        int i = base + k * BK1 + tid;
        if (i < N_) {
            float a0 = anchors[i * 4 + 0], a1 = anchors[i * 4 + 1];
            float a2 = anchors[i * 4 + 2], a3 = anchors[i * 4 + 3];
            float areaA = (a2 - a0) * (a3 - a1);
            float amax = -1.f;
#pragma unroll
            for (int g = 0; g < G_; ++g) {
                float iou = iou_one(a0, a1, a2, a3, areaA,
                                    sgt[g * 4 + 0], sgt[g * 4 + 1],
                                    sgt[g * 4 + 2], sgt[g * 4 + 3]);
                amax = fmaxf(amax, iou);
                // pack (iou, ~i): u64-max == (max iou, first index on tie)
                unsigned long long p =
                    (((unsigned long long)__float_as_uint(iou)) << 32) |
                    (unsigned)(0xFFFFFFFFu - (unsigned)i);
                if (p > best[g]) best[g] = p;
            }
            int8_t lab = -1;
            if (amax < 0.3f) lab = 0;
            if (amax > 0.7f) lab = 1;
            labels[(size_t)b * N_ + i] = lab;
        }
    }

    int lane = tid & 63, wave = tid >> 6;
#pragma unroll
    for (int g = 0; g < G_; ++g) {
        unsigned long long v = best[g];
        for (int m = 32; m >= 1; m >>= 1) {
            unsigned long long o = shfl_xor_u64(v, m);
            if (o > v) v = o;
        }
        if (lane == 0) swb[wave][g] = v;
    }
    __syncthreads();
    if (tid < G_) {
        unsigned long long v = swb[0][tid];
        for (int w = 1; w < BK1 / 64; ++w)
            if (swb[w][tid] > v) v = swb[w][tid];
        blockBest[((size_t)b * G_ + tid) * NB1 + blockIdx.x] = v;
    }
}

// Kernel 2: reduce per-block bests, scatter promotion labels[best]=1.
__global__ void rpn_promote(const unsigned long long* __restrict__ blockBest,
                            int8_t* __restrict__ labels) {
    int bg = blockIdx.x;   // b*G + g
    int lane = threadIdx.x;
    unsigned long long v = 0;
    for (int j = lane; j < NB1; j += 64) {
        unsigned long long x = blockBest[(size_t)bg * NB1 + j];
        if (x > v) v = x;
    }
    for (int m = 32; m >= 1; m >>= 1) {
        unsigned long long o = shfl_xor_u64(v, m);
        if (o > v) v = o;
    }
    if (lane == 0) {
        unsigned idx = 0xFFFFFFFFu - (unsigned)(v & 0xFFFFFFFFull);
        int b = bg / G_;
        labels[(size_t)b * N_ + idx] = 1;
    }
}

// Kernel 3a: per-block pos/neg counts.
__global__ void __launch_bounds__(BK3) rpn_count(
        const int8_t* __restrict__ labels,
        int* __restrict__ posCnt, int* __restrict__ negCnt) {
    int b = blockIdx.y;
    int i = blockIdx.x * BK3 + threadIdx.x;
    int lab = (i < N_) ? labels[(size_t)b * N_ + i] : -1;
    unsigned long long bp = __ballot(lab == 1);
    unsigned long long bn = __ballot(lab == 0);
    __shared__ int sp[BK3 / 64], sn[BK3 / 64];
    int lane = threadIdx.x & 63, wave = threadIdx.x >> 6;
    if (lane == 0) { sp[wave] = __popcll(bp); sn[wave] = __popcll(bn); }
    __syncthreads();
    if (threadIdx.x == 0) {
        int p = 0, n = 0;
        for (int w = 0; w < BK3 / 64; ++w) { p += sp[w]; n += sn[w]; }
        posCnt[b * NB3 + blockIdx.x] = p;
        negCnt[b * NB3 + blockIdx.x] = n;
    }
}

// Kernel 3b: per-batch exclusive scan of block counts (in-place) + totals.
__global__ void __launch_bounds__(256) rpn_scan(
        int* __restrict__ posCnt, int* __restrict__ negCnt,
        int* __restrict__ totPos, int* __restrict__ totNeg) {
    int b = blockIdx.x;
    __shared__ int sp[256], sn[256];
    int tid = threadIdx.x;
    int runP = 0, runN = 0;
    for (int base = 0; base < NB3; base += 256) {
        int idx = base + tid;
        int vp = (idx < NB3) ? posCnt[b * NB3 + idx] : 0;
        int vn = (idx < NB3) ? negCnt[b * NB3 + idx] : 0;
        sp[tid] = vp; sn[tid] = vn;
        __syncthreads();
        for (int off = 1; off < 256; off <<= 1) {
            int tp = 0, tn = 0;
            if (tid >= off) { tp = sp[tid - off]; tn = sn[tid - off]; }
            __syncthreads();
            sp[tid] += tp; sn[tid] += tn;
            __syncthreads();
        }
        if (idx < NB3) {
            posCnt[b * NB3 + idx] = runP + sp[tid] - vp;   // exclusive prefix
            negCnt[b * NB3 + idx] = runN + sn[tid] - vn;
        }
        int lastP = sp[255], lastN = sn[255];
        __syncthreads();
        runP += lastP; runN += lastN;
    }
    if (tid == 0) { totPos[b] = runP; totNeg[b] = runN; }
}

// Kernel 3c: per-anchor global rank -> kept samples; accumulate BCE; record kept positives.
__global__ void __launch_bounds__(BK3) rpn_sample(
        const int8_t* __restrict__ labels, const float* __restrict__ rpn_scores,
        const int* __restrict__ posBase, const int* __restrict__ negBase,
        const int* __restrict__ totPos,
        int* __restrict__ posIdx, float* __restrict__ clsSum) {
    int b = blockIdx.y;
    int tid = threadIdx.x;
    int i = blockIdx.x * BK3 + tid;
    int lab = (i < N_) ? labels[(size_t)b * N_ + i] : -1;
    bool pos = (lab == 1), neg = (lab == 0);
    unsigned long long bp = __ballot(pos), bn = __ballot(neg);
    int lane = tid & 63, wave = tid >> 6;
    unsigned long long ltm = (1ull << lane) - 1ull;
    int pPre = __popcll(bp & ltm), nPre = __popcll(bn & ltm);
    __shared__ int swp[BK3 / 64], swn[BK3 / 64];
    __shared__ float sbce[BK3 / 64];
    if (lane == 0) { swp[wave] = __popcll(bp); swn[wave] = __popcll(bn); }
    __syncthreads();
    int wOffP = 0, wOffN = 0;
    for (int w = 0; w < wave; ++w) { wOffP += swp[w]; wOffN += swn[w]; }

    int npos = min(totPos[b], RPN_BATCH / 2);
    int negQuota = RPN_BATCH - npos;

    float bce = 0.f;
    bool kept = false;
    float t = 0.f;
    if (pos) {
        int rank = posBase[b * NB3 + blockIdx.x] + wOffP + pPre;
        if (rank < RPN_BATCH / 2) {
            kept = true; t = 1.f;
            posIdx[b * (RPN_BATCH / 2) + rank] = i;
        }
    } else if (neg) {
        int rank = negBase[b * NB3 + blockIdx.x] + wOffN + nPre;
        if (rank < negQuota) { kept = true; t = 0.f; }
    }
    if (kept) {
        float l = rpn_scores[(size_t)b * N_ + i];
        bce = fmaxf(l, 0.f) - l * t + log1pf(expf(-fabsf(l)));
    }
    for (int m = 32; m >= 1; m >>= 1) bce += __shfl_xor(bce, m);
    if (lane == 0) sbce[wave] = bce;
    __syncthreads();
    if (tid == 0) {
        float s = 0.f;
        for (int w = 0; w < BK3 / 64; ++w) s += sbce[w];
        if (s != 0.f) atomicAdd(&clsSum[b], s);
    }
}

// Kernel 4: RPN reg loss over kept positives + final combine.
__global__ void __launch_bounds__(128) rpn_final(
        const float* __restrict__ anchors, const float* __restrict__ rpn_deltas,
        const float* __restrict__ gt_boxes, const int* __restrict__ posIdx,
        const int* __restrict__ totPos, const int* __restrict__ totNeg,
        const float* __restrict__ clsSum, float* __restrict__ out) {
    int b = blockIdx.x;
    int tid = threadIdx.x;
    __shared__ float sgt[G_ * 4];
    __shared__ float sred[2];
    if (tid < G_ * 4) sgt[tid] = gt_boxes[b * G_ * 4 + tid];
    __syncthreads();
    int npos = min(totPos[b], RPN_BATCH / 2);
    float regv = 0.f;
    if (tid < npos) {
        int i = posIdx[b * (RPN_BATCH / 2) + tid];
        float a0 = anchors[i * 4 + 0], a1 = anchors[i * 4 + 1];
        float a2 = anchors[i * 4 + 2], a3 = anchors[i * 4 + 3];
        float areaA = (a2 - a0) * (a3 - a1);
        float best = -1.f; int am = 0;
        for (int g = 0; g < G_; ++g) {
            float iou = iou_one(a0, a1, a2, a3, areaA,
                                sgt[g * 4 + 0], sgt[g * 4 + 1],
                                sgt[g * 4 + 2], sgt[g * 4 + 3]);
            if (iou > best) { best = iou; am = g; }  // first-max tie-break
        }
        float t0 = sgt[am * 4 + 0], t1 = sgt[am * 4 + 1];
        float t2 = sgt[am * 4 + 2], t3 = sgt[am * 4 + 3];
        float wa = a2 - a0, ha = a3 - a1;
        float xa = a0 + 0.5f * wa, ya = a1 + 0.5f * ha;
        float wt = t2 - t0, ht = t3 - t1;
        float xt = t0 + 0.5f * wt, yt = t1 + 0.5f * ht;
        float tg0 = (xt - xa) / wa, tg1 = (yt - ya) / ha;
        float tg2 = logf(wt / wa + 1e-6f), tg3 = logf(ht / ha + 1e-6f);
        const float* dp = rpn_deltas + ((size_t)b * N_ + i) * 4;
        regv = smooth_l1(dp[0] - tg0) + smooth_l1(dp[1] - tg1) +
               smooth_l1(dp[2] - tg2) + smooth_l1(dp[3] - tg3);
    }
    int lane = tid & 63, wave = tid >> 6;
    for (int m = 32; m >= 1; m >>= 1) regv += __shfl_xor(regv, m);
    if (lane == 0) sred[wave] = regv;
    __syncthreads();
    if (tid == 0) {
        float regSum = sred[0] + sred[1];
        int kneg = min(totNeg[b], RPN_BATCH - npos);
        float denom = fmaxf((float)(npos + kneg), 1.f);
        float cls = clsSum[b] / denom;
        float reg = (npos > 0) ? regSum / fmaxf((float)npos * 4.f, 1.f) : 0.f;
        atomicAdd(out, cls + reg);
    }
}

// Kernel 5: detection loss, one block per batch.
__global__ void __launch_bounds__(128) det_loss(
        const float* __restrict__ cls_scores, const float* __restrict__ bbox_deltas,
        const float* __restrict__ proposals, const float* __restrict__ gt_boxes,
        const int* __restrict__ gt_labels, float* __restrict__ out) {
    int b = blockIdx.x, tid = threadIdx.x;
    __shared__ float sgt[G_ * 4];
    __shared__ int sgl[G_];
    __shared__ int sassign[P_];
    __shared__ unsigned char sargm[P_];
    __shared__ int ssamp[ROI_BATCH];
    __shared__ float rc[2], rr[2];
    __shared__ int rp[2];
    if (tid < G_ * 4) sgt[tid] = gt_boxes[b * G_ * 4 + tid];
    if (tid < G_) sgl[tid] = gt_labels[b * G_ + tid];
    __syncthreads();

    for (int p = tid; p < P_; p += 128) {
        const float* pr = proposals + ((size_t)b * P_ + p) * 4;
        float a0 = pr[0], a1 = pr[1], a2 = pr[2], a3 = pr[3];
        float areaA = (a2 - a0) * (a3 - a1);
        float best = -1.f; int am = 0;
        for (int g = 0; g < G_; ++g) {
            float iou = iou_one(a0, a1, a2, a3, areaA,
                                sgt[g * 4 + 0], sgt[g * 4 + 1],
                                sgt[g * 4 + 2], sgt[g * 4 + 3]);
            if (iou > best) { best = iou; am = g; }
        }
        sassign[p] = (best >= 0.5f) ? sgl[am] : 0;
        sargm[p] = (unsigned char)am;
    }
    __syncthreads();

    if (tid == 0) {
        // argsort-key sampling: first min(npos,32) positives by index,
        // then negatives by index, then overflow positives by index.
        int cnt = 0, ppos = 0;
        for (int p = 0; p < P_; ++p)
            if (sassign[p] > 0) {
                if (ppos < ROI_BATCH / 4) ssamp[cnt++] = p;
                ppos++;
            }
        for (int p = 0; p < P_ && cnt < ROI_BATCH; ++p)
            if (sassign[p] == 0) ssamp[cnt++] = p;
        if (cnt < ROI_BATCH) {
            int r = 0;
            for (int p = 0; p < P_ && cnt < ROI_BATCH; ++p)
                if (sassign[p] > 0) {
                    if (r >= ROI_BATCH / 4) ssamp[cnt++] = p;
                    r++;
                }
        }
    }
    __syncthreads();

    float clsv = 0.f, regv = 0.f;
    int posc = 0;
    if (tid < ROI_BATCH) {
        int s = ssamp[tid];
        int t = sassign[s];
        const float* row = cls_scores + ((size_t)b * P_ + s) * C_;
        float m = -INFINITY;
        for (int c = 0; c < C_; ++c) m = fmaxf(m, row[c]);
        float se = 0.f;
        for (int c = 0; c < C_; ++c) se += expf(row[c] - m);
        float logp = row[t] - m - logf(se);
        clsv = -logp;
        if (t > 0) {
            posc = 1;
            int g = sargm[s];
            const float* pr = proposals + ((size_t)b * P_ + s) * 4;
            float a0 = pr[0], a1 = pr[1], a2 = pr[2], a3 = pr[3];
            float t0 = sgt[g * 4 + 0], t1 = sgt[g * 4 + 1];
            float t2 = sgt[g * 4 + 2], t3 = sgt[g * 4 + 3];
            float wa = a2 - a0, ha = a3 - a1;
            float xa = a0 + 0.5f * wa, ya = a1 + 0.5f * ha;
            float wt = t2 - t0, ht = t3 - t1;
            float xt = t0 + 0.5f * wt, yt = t1 + 0.5f * ht;
            float tg0 = (xt - xa) / wa, tg1 = (yt - ya) / ha;
            float tg2 = logf(wt / wa + 1e-6f), tg3 = logf(ht / ha + 1e-6f);
            const float* pd = bbox_deltas + ((size_t)b * P_ + s) * (4 * C_) + 4 * t;
            regv = smooth_l1(pd[0] - tg0) + smooth_l1(pd[1] - tg1) +
                   smooth_l1(pd[2] - tg2) + smooth_l1(pd[3] - tg3);
        }
    }
    int lane = tid & 63, wave = tid >> 6;
    for (int m = 32; m >= 1; m >>= 1) {
        clsv += __shfl_xor(clsv, m);
        regv += __shfl_xor(regv, m);
        posc += __shfl_xor(posc, m);
    }
    if (lane == 0) { rc[wave] = clsv; rr[wave] = regv; rp[wave] = posc; }
    __syncthreads();
    if (tid == 0) {
        float cls = (rc[0] + rc[1]) / (float)ROI_BATCH;
        int np = rp[0] + rp[1];
        float regSum = rr[0] + rr[1];
        float reg = (np > 0) ? regSum / fmaxf((float)np * 4.f, 1.f) : 0.f;
        atomicAdd(out, cls + reg);
    }
}

extern "C" void kernel_launch(void* const* d_in, const int* in_sizes, int n_in,
                              void* d_out, int out_size, void* d_ws, size_t ws_size,
                              hipStream_t stream) {
    const float* rpn_scores  = (const float*)d_in[0];
    const float* rpn_deltas  = (const float*)d_in[1];
    const float* cls_scores  = (const float*)d_in[2];
    const float* bbox_deltas = (const float*)d_in[3];
    const float* anchors     = (const float*)d_in[4];
    const float* proposals   = (const float*)d_in[5];
    const float* gt_boxes    = (const float*)d_in[6];
    const int*   gt_labels   = (const int*)d_in[7];
    float* out = (float*)d_out;

    char* ws = (char*)d_ws;
    size_t off = 0;
    auto alloc = [&](size_t bytes) -> char* {
        size_t o = (off + 255) & ~(size_t)255;
        off = o + bytes;
        return ws + o;
    };
    int8_t* labels = (int8_t*)alloc((size_t)B_ * N_);
    unsigned long long* blockBest =
        (unsigned long long*)alloc((size_t)B_ * G_ * NB1 * 8);
    int* posCnt = (int*)alloc((size_t)B_ * NB3 * 4);
    int* negCnt = (int*)alloc((size_t)B_ * NB3 * 4);
    int* totPos = (int*)alloc(B_ * 4);
    int* totNeg = (int*)alloc(B_ * 4);
    int* posIdx = (int*)alloc((size_t)B_ * (RPN_BATCH / 2) * 4);
    float* clsSum = (float*)alloc(B_ * 4);

    hipMemsetAsync(clsSum, 0, B_ * sizeof(float), stream);
    hipMemsetAsync(out, 0, (size_t)out_size * sizeof(float), stream);

    rpn_assign<<<dim3(NB1, B_), BK1, 0, stream>>>(anchors, gt_boxes, labels, blockBest);
    rpn_promote<<<B_ * G_, 64, 0, stream>>>(blockBest, labels);
    rpn_count<<<dim3(NB3, B_), BK3, 0, stream>>>(labels, posCnt, negCnt);
    rpn_scan<<<B_, 256, 0, stream>>>(posCnt, negCnt, totPos, totNeg);
    rpn_sample<<<dim3(NB3, B_), BK3, 0, stream>>>(labels, rpn_scores, posCnt, negCnt,
                                                  totPos, posIdx, clsSum);
    rpn_final<<<B_, 128, 0, stream>>>(anchors, rpn_deltas, gt_boxes, posIdx,
                                      totPos, totNeg, clsSum, out);
    det_loss<<<B_, 128, 0, stream>>>(cls_scores, bbox_deltas, proposals, gt_boxes,
                                     gt_labels, out);
}

// Round 2
// 225.654 us; speedup vs baseline: 1.2477x; 1.2477x over previous
//
#include <hip/hip_runtime.h>
#include <math.h>
#include <stdint.h>

#define B_ 4
#define N_ 250000
#define P_ 1000
#define G_ 32
#define C_ 81
#define RPN_BATCH 256
#define ROI_BATCH 128

#define APT 4                         // anchors per thread in rpn_assign
#define BK1 256
#define ANCH_PER_BLK (BK1 * APT)      // 1024
#define NB1 ((N_ + ANCH_PER_BLK - 1) / ANCH_PER_BLK)   // 245
#define BK3 256
#define NB3 ((N_ + BK3 - 1) / BK3)    // 977

__device__ __forceinline__ float iou_one(float a0, float a1, float a2, float a3,
                                         float areaA,
                                         float b0, float b1, float b2, float b3) {
    float ltx = fmaxf(a0, b0), lty = fmaxf(a1, b1);
    float rbx = fminf(a2, b2), rby = fminf(a3, b3);
    float w = fmaxf(rbx - ltx, 0.f), h = fmaxf(rby - lty, 0.f);
    float inter = w * h;
    float areaB = (b2 - b0) * (b3 - b1);
    return inter / (areaA + areaB - inter + 1e-6f);
}

__device__ __forceinline__ unsigned long long shfl_xor_u64(unsigned long long v, int m) {
    unsigned lo = (unsigned)v, hi = (unsigned)(v >> 32);
    lo = __shfl_xor(lo, m);
    hi = __shfl_xor(hi, m);
    return ((unsigned long long)hi << 32) | lo;
}

__device__ __forceinline__ float smooth_l1(float x) {
    float ax = fabsf(x);
    return (ax < 1.f) ? 0.5f * x * x : ax - 0.5f;
}

// Kernel 1: per-anchor labels (thresholds on max_iou) + per-block per-gt best anchor.
__global__ void __launch_bounds__(BK1) rpn_assign(
        const float* __restrict__ anchors, const float* __restrict__ gt_boxes,
        int8_t* __restrict__ labels, unsigned long long* __restrict__ blockBest) {
    __shared__ float sgt[G_ * 4];
    __shared__ unsigned long long swb[BK1 / 64][G_];
    int b = blockIdx.y;
    int tid = threadIdx.x;
    if (tid < G_ * 4) sgt[tid] = gt_boxes[b * G_ * 4 + tid];
    __syncthreads();

    unsigned long long best[G_];
#pragma unroll
    for (int g = 0; g < G_; ++g) best[g] = 0ull;

    int base = blockIdx.x * ANCH_PER_BLK;
    for (int k = 0; k < APT; ++k) {
        int i = base + k * BK1 + tid;
        if (i < N_) {
            float a0 = anchors[i * 4 + 0], a1 = anchors[i * 4 + 1];
            float a2 = anchors[i * 4 + 2], a3 = anchors[i * 4 + 3];
            float areaA = (a2 - a0) * (a3 - a1);
            float amax = -1.f;
#pragma unroll
            for (int g = 0; g < G_; ++g) {
                float iou = iou_one(a0, a1, a2, a3, areaA,
                                    sgt[g * 4 + 0], sgt[g * 4 + 1],
                                    sgt[g * 4 + 2], sgt[g * 4 + 3]);
                amax = fmaxf(amax, iou);
                // pack (iou, ~i): u64-max == (max iou, first index on tie)
                unsigned long long p =
                    (((unsigned long long)__float_as_uint(iou)) << 32) |
                    (unsigned)(0xFFFFFFFFu - (unsigned)i);
                if (p > best[g]) best[g] = p;
            }
            int8_t lab = -1;
            if (amax < 0.3f) lab = 0;
            if (amax > 0.7f) lab = 1;
            labels[(size_t)b * N_ + i] = lab;
        }
    }

    int lane = tid & 63, wave = tid >> 6;
#pragma unroll
    for (int g = 0; g < G_; ++g) {
        unsigned long long v = best[g];
        for (int m = 32; m >= 1; m >>= 1) {
            unsigned long long o = shfl_xor_u64(v, m);
            if (o > v) v = o;
        }
        if (lane == 0) swb[wave][g] = v;
    }
    __syncthreads();
    if (tid < G_) {
        unsigned long long v = swb[0][tid];
        for (int w = 1; w < BK1 / 64; ++w)
            if (swb[w][tid] > v) v = swb[w][tid];
        blockBest[((size_t)b * G_ + tid) * NB1 + blockIdx.x] = v;
    }
}

// Kernel 2: reduce per-block bests, scatter promotion labels[best]=1.
__global__ void rpn_promote(const unsigned long long* __restrict__ blockBest,
                            int8_t* __restrict__ labels) {
    int bg = blockIdx.x;   // b*G + g
    int lane = threadIdx.x;
    unsigned long long v = 0;
    for (int j = lane; j < NB1; j += 64) {
        unsigned long long x = blockBest[(size_t)bg * NB1 + j];
        if (x > v) v = x;
    }
    for (int m = 32; m >= 1; m >>= 1) {
        unsigned long long o = shfl_xor_u64(v, m);
        if (o > v) v = o;
    }
    if (lane == 0) {
        unsigned idx = 0xFFFFFFFFu - (unsigned)(v & 0xFFFFFFFFull);
        int b = bg / G_;
        labels[(size_t)b * N_ + idx] = 1;
    }
}

// Kernel 3a: per-block pos/neg counts.
__global__ void __launch_bounds__(BK3) rpn_count(
        const int8_t* __restrict__ labels,
        int* __restrict__ posCnt, int* __restrict__ negCnt) {
    int b = blockIdx.y;
    int i = blockIdx.x * BK3 + threadIdx.x;
    int lab = (i < N_) ? labels[(size_t)b * N_ + i] : -1;
    unsigned long long bp = __ballot(lab == 1);
    unsigned long long bn = __ballot(lab == 0);
    __shared__ int sp[BK3 / 64], sn[BK3 / 64];
    int lane = threadIdx.x & 63, wave = threadIdx.x >> 6;
    if (lane == 0) { sp[wave] = __popcll(bp); sn[wave] = __popcll(bn); }
    __syncthreads();
    if (threadIdx.x == 0) {
        int p = 0, n = 0;
        for (int w = 0; w < BK3 / 64; ++w) { p += sp[w]; n += sn[w]; }
        posCnt[b * NB3 + blockIdx.x] = p;
        negCnt[b * NB3 + blockIdx.x] = n;
    }
}

// Kernel 3b: per-batch exclusive scan of block counts (in-place) + totals.
__global__ void __launch_bounds__(256) rpn_scan(
        int* __restrict__ posCnt, int* __restrict__ negCnt,
        int* __restrict__ totPos, int* __restrict__ totNeg) {
    int b = blockIdx.x;
    __shared__ int sp[256], sn[256];
    int tid = threadIdx.x;
    int runP = 0, runN = 0;
    for (int base = 0; base < NB3; base += 256) {
        int idx = base + tid;
        int vp = (idx < NB3) ? posCnt[b * NB3 + idx] : 0;
        int vn = (idx < NB3) ? negCnt[b * NB3 + idx] : 0;
        sp[tid] = vp; sn[tid] = vn;
        __syncthreads();
        for (int off = 1; off < 256; off <<= 1) {
            int tp = 0, tn = 0;
            if (tid >= off) { tp = sp[tid - off]; tn = sn[tid - off]; }
            __syncthreads();
            sp[tid] += tp; sn[tid] += tn;
            __syncthreads();
        }
        if (idx < NB3) {
            posCnt[b * NB3 + idx] = runP + sp[tid] - vp;   // exclusive prefix
            negCnt[b * NB3 + idx] = runN + sn[tid] - vn;
        }
        int lastP = sp[255], lastN = sn[255];
        __syncthreads();
        runP += lastP; runN += lastN;
    }
    if (tid == 0) { totPos[b] = runP; totNeg[b] = runN; }
}

// Kernel 3c: per-anchor global rank -> kept samples; accumulate BCE; record kept positives.
__global__ void __launch_bounds__(BK3) rpn_sample(
        const int8_t* __restrict__ labels, const float* __restrict__ rpn_scores,
        const int* __restrict__ posBase, const int* __restrict__ negBase,
        const int* __restrict__ totPos,
        int* __restrict__ posIdx, float* __restrict__ clsSum) {
    int b = blockIdx.y;
    int tid = threadIdx.x;
    int i = blockIdx.x * BK3 + tid;
    int lab = (i < N_) ? labels[(size_t)b * N_ + i] : -1;
    bool pos = (lab == 1), neg = (lab == 0);
    unsigned long long bp = __ballot(pos), bn = __ballot(neg);
    int lane = tid & 63, wave = tid >> 6;
    unsigned long long ltm = (1ull << lane) - 1ull;
    int pPre = __popcll(bp & ltm), nPre = __popcll(bn & ltm);
    __shared__ int swp[BK3 / 64], swn[BK3 / 64];
    __shared__ float sbce[BK3 / 64];
    if (lane == 0) { swp[wave] = __popcll(bp); swn[wave] = __popcll(bn); }
    __syncthreads();
    int wOffP = 0, wOffN = 0;
    for (int w = 0; w < wave; ++w) { wOffP += swp[w]; wOffN += swn[w]; }

    int npos = min(totPos[b], RPN_BATCH / 2);
    int negQuota = RPN_BATCH - npos;

    float bce = 0.f;
    bool kept = false;
    float t = 0.f;
    if (pos) {
        int rank = posBase[b * NB3 + blockIdx.x] + wOffP + pPre;
        if (rank < RPN_BATCH / 2) {
            kept = true; t = 1.f;
            posIdx[b * (RPN_BATCH / 2) + rank] = i;
        }
    } else if (neg) {
        int rank = negBase[b * NB3 + blockIdx.x] + wOffN + nPre;
        if (rank < negQuota) { kept = true; t = 0.f; }
    }
    if (kept) {
        float l = rpn_scores[(size_t)b * N_ + i];
        bce = fmaxf(l, 0.f) - l * t + log1pf(expf(-fabsf(l)));
    }
    for (int m = 32; m >= 1; m >>= 1) bce += __shfl_xor(bce, m);
    if (lane == 0) sbce[wave] = bce;
    __syncthreads();
    if (tid == 0) {
        float s = 0.f;
        for (int w = 0; w < BK3 / 64; ++w) s += sbce[w];
        if (s != 0.f) atomicAdd(&clsSum[b], s);
    }
}

// Kernel 4: RPN reg loss over kept positives + final combine.
__global__ void __launch_bounds__(128) rpn_final(
        const float* __restrict__ anchors, const float* __restrict__ rpn_deltas,
        const float* __restrict__ gt_boxes, const int* __restrict__ posIdx,
        const int* __restrict__ totPos, const int* __restrict__ totNeg,
        const float* __restrict__ clsSum, float* __restrict__ out) {
    int b = blockIdx.x;
    int tid = threadIdx.x;
    __shared__ float sgt[G_ * 4];
    __shared__ float sred[2];
    if (tid < G_ * 4) sgt[tid] = gt_boxes[b * G_ * 4 + tid];
    __syncthreads();
    int npos = min(totPos[b], RPN_BATCH / 2);
    float regv = 0.f;
    if (tid < npos) {
        int i = posIdx[b * (RPN_BATCH / 2) + tid];
        float a0 = anchors[i * 4 + 0], a1 = anchors[i * 4 + 1];
        float a2 = anchors[i * 4 + 2], a3 = anchors[i * 4 + 3];
        float areaA = (a2 - a0) * (a3 - a1);
        float best = -1.f; int am = 0;
        for (int g = 0; g < G_; ++g) {
            float iou = iou_one(a0, a1, a2, a3, areaA,
                                sgt[g * 4 + 0], sgt[g * 4 + 1],
                                sgt[g * 4 + 2], sgt[g * 4 + 3]);
            if (iou > best) { best = iou; am = g; }  // first-max tie-break
        }
        float t0 = sgt[am * 4 + 0], t1 = sgt[am * 4 + 1];
        float t2 = sgt[am * 4 + 2], t3 = sgt[am * 4 + 3];
        float wa = a2 - a0, ha = a3 - a1;
        float xa = a0 + 0.5f * wa, ya = a1 + 0.5f * ha;
        float wt = t2 - t0, ht = t3 - t1;
        float xt = t0 + 0.5f * wt, yt = t1 + 0.5f * ht;
        float tg0 = (xt - xa) / wa, tg1 = (yt - ya) / ha;
        float tg2 = logf(wt / wa + 1e-6f), tg3 = logf(ht / ha + 1e-6f);
        const float* dp = rpn_deltas + ((size_t)b * N_ + i) * 4;
        regv = smooth_l1(dp[0] - tg0) + smooth_l1(dp[1] - tg1) +
               smooth_l1(dp[2] - tg2) + smooth_l1(dp[3] - tg3);
    }
    int lane = tid & 63, wave = tid >> 6;
    for (int m = 32; m >= 1; m >>= 1) regv += __shfl_xor(regv, m);
    if (lane == 0) sred[wave] = regv;
    __syncthreads();
    if (tid == 0) {
        float regSum = sred[0] + sred[1];
        int kneg = min(totNeg[b], RPN_BATCH - npos);
        float denom = fmaxf((float)(npos + kneg), 1.f);
        float cls = clsSum[b] / denom;
        float reg = (npos > 0) ? regSum / fmaxf((float)npos * 4.f, 1.f) : 0.f;
        atomicAdd(out, cls + reg);
    }
}

// Kernel 5: detection loss, one block per batch. Sampling via parallel rank
// arithmetic (stable-argsort equivalence), NOT a serial thread-0 loop.
__global__ void __launch_bounds__(128) det_loss(
        const float* __restrict__ cls_scores, const float* __restrict__ bbox_deltas,
        const float* __restrict__ proposals, const float* __restrict__ gt_boxes,
        const int* __restrict__ gt_labels, float* __restrict__ out) {
    int b = blockIdx.x, tid = threadIdx.x;
    __shared__ float sgt[G_ * 4];
    __shared__ int sgl[G_];
    __shared__ short sassign[P_];
    __shared__ unsigned char sargm[P_];
    __shared__ int scnt[128];
    __shared__ int ssamp[ROI_BATCH];
    __shared__ float rc[2], rr[2];
    __shared__ int rp[2];
    if (tid < G_ * 4) sgt[tid] = gt_boxes[b * G_ * 4 + tid];
    if (tid < G_) sgl[tid] = gt_labels[b * G_ + tid];
    __syncthreads();

    for (int p = tid; p < P_; p += 128) {
        const float* pr = proposals + ((size_t)b * P_ + p) * 4;
        float a0 = pr[0], a1 = pr[1], a2 = pr[2], a3 = pr[3];
        float areaA = (a2 - a0) * (a3 - a1);
        float best = -1.f; int am = 0;
        for (int g = 0; g < G_; ++g) {
            float iou = iou_one(a0, a1, a2, a3, areaA,
                                sgt[g * 4 + 0], sgt[g * 4 + 1],
                                sgt[g * 4 + 2], sgt[g * 4 + 3]);
            if (iou > best) { best = iou; am = g; }
        }
        sassign[p] = (best >= 0.5f) ? (short)sgl[am] : (short)0;
        sargm[p] = (unsigned char)am;
    }
    __syncthreads();

    // --- parallel sampling: slot(p) from pos/neg ranks ---
    // argsort key order: positives with pos_rank<32 (by pos_rank), then
    // negatives (by index), then overflow positives (by index).
    const int CH = 8;                 // chunk per thread, 128*8=1024 >= P_
    int c0 = tid * CH;
    int cnt = 0;
    for (int k = 0; k < CH; ++k) {
        int p = c0 + k;
        if (p < P_ && sassign[p] > 0) cnt++;
    }
    scnt[tid] = cnt;
    __syncthreads();
    for (int off = 1; off < 128; off <<= 1) {          // inclusive scan
        int v = (tid >= off) ? scnt[tid - off] : 0;
        __syncthreads();
        scnt[tid] += v;
        __syncthreads();
    }
    int npos_total = scnt[127];
    int npos_kept = min(npos_total, ROI_BATCH / 4);
    int nneg_total = P_ - npos_total;
    int prefix = scnt[tid] - cnt;                      // exclusive: #pos in [0,c0)
    for (int k = 0; k < CH; ++k) {
        int p = c0 + k;
        if (p >= P_) break;
        int slot;
        if (sassign[p] > 0) {
            if (prefix < ROI_BATCH / 4) slot = prefix;                         // kept pos
            else slot = npos_kept + nneg_total + (prefix - ROI_BATCH / 4);     // overflow pos
            prefix++;
        } else {
            int nr = p - prefix;                        // neg rank = idx - pos prefix
            slot = npos_kept + nr;
        }
        if (slot < ROI_BATCH) ssamp[slot] = p;
    }
    __syncthreads();

    float clsv = 0.f, regv = 0.f;
    int posc = 0;
    if (tid < ROI_BATCH) {
        int s = ssamp[tid];
        int t = sassign[s];
        const float* row = cls_scores + ((size_t)b * P_ + s) * C_;
        float m = -INFINITY;
        for (int c = 0; c < C_; ++c) m = fmaxf(m, row[c]);
        float se = 0.f;
        for (int c = 0; c < C_; ++c) se += expf(row[c] - m);
        float logp = row[t] - m - logf(se);
        clsv = -logp;
        if (t > 0) {
            posc = 1;
            int g = sargm[s];
            const float* pr = proposals + ((size_t)b * P_ + s) * 4;
            float a0 = pr[0], a1 = pr[1], a2 = pr[2], a3 = pr[3];
            float t0 = sgt[g * 4 + 0], t1 = sgt[g * 4 + 1];
            float t2 = sgt[g * 4 + 2], t3 = sgt[g * 4 + 3];
            float wa = a2 - a0, ha = a3 - a1;
            float xa = a0 + 0.5f * wa, ya = a1 + 0.5f * ha;
            float wt = t2 - t0, ht = t3 - t1;
            float xt = t0 + 0.5f * wt, yt = t1 + 0.5f * ht;
            float tg0 = (xt - xa) / wa, tg1 = (yt - ya) / ha;
            float tg2 = logf(wt / wa + 1e-6f), tg3 = logf(ht / ha + 1e-6f);
            const float* pd = bbox_deltas + ((size_t)b * P_ + s) * (4 * C_) + 4 * t;
            regv = smooth_l1(pd[0] - tg0) + smooth_l1(pd[1] - tg1) +
                   smooth_l1(pd[2] - tg2) + smooth_l1(pd[3] - tg3);
        }
    }
    int lane = tid & 63, wave = tid >> 6;
    for (int m = 32; m >= 1; m >>= 1) {
        clsv += __shfl_xor(clsv, m);
        regv += __shfl_xor(regv, m);
        posc += __shfl_xor(posc, m);
    }
    if (lane == 0) { rc[wave] = clsv; rr[wave] = regv; rp[wave] = posc; }
    __syncthreads();
    if (tid == 0) {
        float cls = (rc[0] + rc[1]) / (float)ROI_BATCH;
        int np = rp[0] + rp[1];
        float regSum = rr[0] + rr[1];
        float reg = (np > 0) ? regSum / fmaxf((float)np * 4.f, 1.f) : 0.f;
        atomicAdd(out, cls + reg);
    }
}

extern "C" void kernel_launch(void* const* d_in, const int* in_sizes, int n_in,
                              void* d_out, int out_size, void* d_ws, size_t ws_size,
                              hipStream_t stream) {
    const float* rpn_scores  = (const float*)d_in[0];
    const float* rpn_deltas  = (const float*)d_in[1];
    const float* cls_scores  = (const float*)d_in[2];
    const float* bbox_deltas = (const float*)d_in[3];
    const float* anchors     = (const float*)d_in[4];
    const float* proposals   = (const float*)d_in[5];
    const float* gt_boxes    = (const float*)d_in[6];
    const int*   gt_labels   = (const int*)d_in[7];
    float* out = (float*)d_out;

    char* ws = (char*)d_ws;
    size_t off = 0;
    auto alloc = [&](size_t bytes) -> char* {
        size_t o = (off + 255) & ~(size_t)255;
        off = o + bytes;
        return ws + o;
    };
    int8_t* labels = (int8_t*)alloc((size_t)B_ * N_);
    unsigned long long* blockBest =
        (unsigned long long*)alloc((size_t)B_ * G_ * NB1 * 8);
    int* posCnt = (int*)alloc((size_t)B_ * NB3 * 4);
    int* negCnt = (int*)alloc((size_t)B_ * NB3 * 4);
    int* totPos = (int*)alloc(B_ * 4);
    int* totNeg = (int*)alloc(B_ * 4);
    int* posIdx = (int*)alloc((size_t)B_ * (RPN_BATCH / 2) * 4);
    float* clsSum = (float*)alloc(B_ * 4);

    hipMemsetAsync(clsSum, 0, B_ * sizeof(float), stream);
    hipMemsetAsync(out, 0, (size_t)out_size * sizeof(float), stream);

    rpn_assign<<<dim3(NB1, B_), BK1, 0, stream>>>(anchors, gt_boxes, labels, blockBest);
    rpn_promote<<<B_ * G_, 64, 0, stream>>>(blockBest, labels);
    rpn_count<<<dim3(NB3, B_), BK3, 0, stream>>>(labels, posCnt, negCnt);
    rpn_scan<<<B_, 256, 0, stream>>>(posCnt, negCnt, totPos, totNeg);
    rpn_sample<<<dim3(NB3, B_), BK3, 0, stream>>>(labels, rpn_scores, posCnt, negCnt,
                                                  totPos, posIdx, clsSum);
    rpn_final<<<B_, 128, 0, stream>>>(anchors, rpn_deltas, gt_boxes, posIdx,
                                      totPos, totNeg, clsSum, out);
    det_loss<<<B_, 128, 0, stream>>>(cls_scores, bbox_deltas, proposals, gt_boxes,
                                     gt_labels, out);
}

// Round 3
// 189.753 us; speedup vs baseline: 1.4837x; 1.1892x over previous
//
#include <hip/hip_runtime.h>
#include <math.h>
#include <stdint.h>

#define B_ 4
#define N_ 250000
#define P_ 1000
#define G_ 32
#define C_ 81
#define RPN_BATCH 256
#define ROI_BATCH 128

#define ABLK 1024                                   // anchors per block
#define NBA ((N_ + ABLK - 1) / ABLK)                // 245

__device__ __forceinline__ float iou_one(float a0, float a1, float a2, float a3,
                                         float areaA,
                                         float b0, float b1, float b2, float b3) {
    float ltx = fmaxf(a0, b0), lty = fmaxf(a1, b1);
    float rbx = fminf(a2, b2), rby = fminf(a3, b3);
    float w = fmaxf(rbx - ltx, 0.f), h = fmaxf(rby - lty, 0.f);
    float inter = w * h;
    float areaB = (b2 - b0) * (b3 - b1);
    return inter / (areaA + areaB - inter + 1e-6f);
}

__device__ __forceinline__ unsigned long long shfl_xor_u64(unsigned long long v, int m) {
    unsigned lo = (unsigned)v, hi = (unsigned)(v >> 32);
    lo = __shfl_xor(lo, m);
    hi = __shfl_xor(hi, m);
    return ((unsigned long long)hi << 32) | lo;
}

__device__ __forceinline__ float smooth_l1(float x) {
    float ax = fabsf(x);
    return (ax < 1.f) ? 0.5f * x * x : ax - 0.5f;
}

// Kernel 1: labels + per-block pos/neg counts + per-(block,gt) best anchor.
// Wave w of each block handles gts [8w, 8w+8) for ALL ABLK anchors (gt data in
// registers, anchors staged in LDS, no division in the hot loop).
__global__ void __launch_bounds__(256, 4) rpn_assign(
        const float* __restrict__ anchors, const float* __restrict__ gt_boxes,
        int8_t* __restrict__ labels, int* __restrict__ posCnt, int* __restrict__ negCnt,
        unsigned long long* __restrict__ blockBest) {
    __shared__ float4 sA[ABLK];                 // 16 KB
    __shared__ float sArea[ABLK];               // 4 KB
    __shared__ float sGt[G_ * 5];               // x0,y0,x1,y1, areaB+1e-6
    __shared__ unsigned char sPart[4][ABLK];    // 4 KB per-wave label partials
    __shared__ int sCnt[8];

    int b = blockIdx.y, tid = threadIdx.x;
    int base = blockIdx.x * ABLK;

    for (int t = tid; t < ABLK; t += 256) {
        int ai = base + t;
        float4 v = make_float4(0.f, 0.f, 0.f, 0.f);
        if (ai < N_) v = ((const float4*)anchors)[ai];
        sA[t] = v;
        sArea[t] = (v.z - v.x) * (v.w - v.y);
    }
    if (tid < G_) {
        float4 g = ((const float4*)gt_boxes)[b * G_ + tid];
        sGt[tid * 5 + 0] = g.x; sGt[tid * 5 + 1] = g.y;
        sGt[tid * 5 + 2] = g.z; sGt[tid * 5 + 3] = g.w;
        sGt[tid * 5 + 4] = (g.z - g.x) * (g.w - g.y) + 1e-6f;
    }
    __syncthreads();

    int lane = tid & 63, wave = tid >> 6;

    float g0[8], g1[8], g2[8], g3[8], gae[8];
#pragma unroll
    for (int j = 0; j < 8; ++j) {
        int gg = wave * 8 + j;
        g0[j] = sGt[gg * 5 + 0]; g1[j] = sGt[gg * 5 + 1];
        g2[j] = sGt[gg * 5 + 2]; g3[j] = sGt[gg * 5 + 3];
        gae[j] = sGt[gg * 5 + 4];
    }

    // best per gt as (inter, denom, idx); iou_a>iou_b <=> ia*db > ib*da
    float bi[8], bd[8]; int bx[8];
#pragma unroll
    for (int j = 0; j < 8; ++j) { bi[j] = 0.f; bd[j] = 1.f; bx[j] = 0; }

    for (int k = 0; k < ABLK / 64; ++k) {
        int a = k * 64 + lane;
        float4 A = sA[a];
        float areaA = sArea[a];
        int gidx = base + a;
        float acc03 = 1e30f, acc07 = 1e30f;
#pragma unroll
        for (int j = 0; j < 8; ++j) {
            float ltx = fmaxf(A.x, g0[j]), lty = fmaxf(A.y, g1[j]);
            float rbx = fminf(A.z, g2[j]), rby = fminf(A.w, g3[j]);
            float w = fmaxf(rbx - ltx, 0.f), h = fmaxf(rby - lty, 0.f);
            float inter = w * h;
            float d = (areaA + gae[j]) - inter;          // includes +1e-6
            acc03 = fminf(acc03, fmaf(0.3f, d, -inter)); // >0 => iou<0.3
            acc07 = fminf(acc07, fmaf(0.7f, d, -inter)); // <0 => iou>0.7
            float p1 = inter * bd[j], p2 = bi[j] * d;
            if (p1 > p2) { bi[j] = inter; bd[j] = d; bx[j] = gidx; } // strict > keeps first idx
        }
        unsigned char byte = (unsigned char)(((acc07 < 0.f) ? 2 : 0) | ((acc03 > 0.f) ? 1 : 0));
        sPart[wave][a] = byte;
    }

    // cross-lane reduce each gt's best; tie -> smaller anchor idx
#pragma unroll
    for (int j = 0; j < 8; ++j) {
        float i_ = bi[j], d_ = bd[j]; int x_ = bx[j];
        for (int m = 32; m >= 1; m >>= 1) {
            float oi = __shfl_xor(i_, m), od = __shfl_xor(d_, m);
            int ox = __shfl_xor(x_, m);
            float pa = oi * d_, pb = i_ * od;
            bool take = (pa > pb) || (pa == pb && ox < x_);
            if (take) { i_ = oi; d_ = od; x_ = ox; }
        }
        if (lane == 0) {
            float iou = i_ / d_;                         // exact div, once per (block,gt)
            unsigned long long pk =
                (((unsigned long long)__float_as_uint(iou)) << 32) |
                (unsigned)(0xFFFFFFFFu - (unsigned)x_);
            blockBest[((size_t)b * G_ + wave * 8 + j) * NBA + blockIdx.x] = pk;
        }
    }
    __syncthreads();

    // combine 4 wave-partials -> labels (word writes) + pos/neg counts
    unsigned u0 = ((const unsigned*)&sPart[0][0])[tid];
    unsigned u1 = ((const unsigned*)&sPart[1][0])[tid];
    unsigned u2 = ((const unsigned*)&sPart[2][0])[tid];
    unsigned u3 = ((const unsigned*)&sPart[3][0])[tid];
    unsigned andb = u0 & u1 & u2 & u3;   // bit0/byte: allBelow03
    unsigned orb  = u0 | u1 | u2 | u3;   // bit1/byte: anyAbove07
    int gbase = base + tid * 4;
    unsigned outw = 0; int cp = 0, cn = 0;
#pragma unroll
    for (int j = 0; j < 4; ++j) {
        int above = (orb >> (8 * j + 1)) & 1;
        int below = (andb >> (8 * j)) & 1;
        int lab = above ? 1 : (below ? 0 : -1);
        if (gbase + j < N_) { cp += (lab == 1); cn += (lab == 0); }
        outw |= ((unsigned)(unsigned char)(char)lab) << (8 * j);
    }
    if (gbase < N_)   // valid remainder is word-aligned (N_%4==0, tail=144)
        ((unsigned*)labels)[(((size_t)b * N_ + base) >> 2) + tid] = outw;

    for (int m = 32; m >= 1; m >>= 1) { cp += __shfl_xor(cp, m); cn += __shfl_xor(cn, m); }
    if (lane == 0) { sCnt[wave] = cp; sCnt[4 + wave] = cn; }
    __syncthreads();
    if (tid == 0) {
        posCnt[b * NBA + blockIdx.x] = sCnt[0] + sCnt[1] + sCnt[2] + sCnt[3];
        negCnt[b * NBA + blockIdx.x] = sCnt[4] + sCnt[5] + sCnt[6] + sCnt[7];
    }
}

// Kernel 2: per-gt global winner, dedupe, promote label + adjust counts.
__global__ void __launch_bounds__(256) rpn_promote(
        const unsigned long long* __restrict__ blockBest, int8_t* __restrict__ labels,
        int* __restrict__ posCnt, int* __restrict__ negCnt) {
    int b = blockIdx.x, tid = threadIdx.x;
    int g = tid >> 3, sub = tid & 7;   // 32 gts x 8 threads
    unsigned long long v = 0;
    for (int j = sub; j < NBA; j += 8) {
        unsigned long long x = blockBest[((size_t)b * G_ + g) * NBA + j];
        if (x > v) v = x;
    }
    for (int m = 4; m >= 1; m >>= 1) {
        unsigned long long o = shfl_xor_u64(v, m);
        if (o > v) v = o;
    }
    __shared__ unsigned wIdx[G_];
    if (sub == 0) wIdx[g] = 0xFFFFFFFFu - (unsigned)(v & 0xFFFFFFFFull);
    __syncthreads();
    if (tid < G_) {
        unsigned w = wIdx[tid];
        bool first = true;
        for (int j = 0; j < tid; ++j) if (wIdx[j] == w) first = false;
        if (first) {
            size_t li = (size_t)b * N_ + w;
            int8_t old = labels[li];
            labels[li] = 1;
            int blk = (int)(w / ABLK);
            if (old != 1) atomicAdd(&posCnt[b * NBA + blk], 1);
            if (old == 0) atomicAdd(&negCnt[b * NBA + blk], -1);
        }
    }
}

// Kernel 3: exclusive scan of per-block counts (NBA=245 fits one 256-chunk).
__global__ void __launch_bounds__(256) rpn_scan(
        int* __restrict__ posCnt, int* __restrict__ negCnt,
        int* __restrict__ totPos, int* __restrict__ totNeg) {
    int b = blockIdx.x, tid = threadIdx.x;
    __shared__ int sp[256], sn[256];
    int vp = (tid < NBA) ? posCnt[b * NBA + tid] : 0;
    int vn = (tid < NBA) ? negCnt[b * NBA + tid] : 0;
    sp[tid] = vp; sn[tid] = vn;
    __syncthreads();
    for (int off = 1; off < 256; off <<= 1) {
        int tp = 0, tn = 0;
        if (tid >= off) { tp = sp[tid - off]; tn = sn[tid - off]; }
        __syncthreads();
        sp[tid] += tp; sn[tid] += tn;
        __syncthreads();
    }
    if (tid < NBA) { posCnt[b * NBA + tid] = sp[tid] - vp; negCnt[b * NBA + tid] = sn[tid] - vn; }
    if (tid == 0) { totPos[b] = sp[255]; totNeg[b] = sn[255]; }
}

// Kernel 4: ranks -> kept samples; BCE sum; reg loss for kept positives.
__global__ void __launch_bounds__(256) rpn_sample(
        const int8_t* __restrict__ labels, const float* __restrict__ rpn_scores,
        const float* __restrict__ rpn_deltas, const float* __restrict__ anchors,
        const float* __restrict__ gt_boxes,
        const int* __restrict__ posBase, const int* __restrict__ negBase,
        const int* __restrict__ totPos, float* __restrict__ sums) {
    int b = blockIdx.y, tid = threadIdx.x;
    int base = blockIdx.x * ABLK;
    __shared__ float sg[G_ * 4];
    __shared__ int swP[4], swN[4];
    __shared__ float sred[8];
    if (tid < G_ * 4) sg[tid] = gt_boxes[b * G_ * 4 + tid];

    int gbase = base + tid * 4;
    unsigned word = 0xFFFFFFFFu;   // all -1
    if (gbase < N_)
        word = ((const unsigned*)labels)[(((size_t)b * N_ + base) >> 2) + tid];
    int lab[4]; int cntP = 0, cntN = 0;
#pragma unroll
    for (int j = 0; j < 4; ++j) {
        lab[j] = (int)(char)((word >> (8 * j)) & 0xFF);
        cntP += (lab[j] == 1); cntN += (lab[j] == 0);
    }
    int lane = tid & 63, wave = tid >> 6;
    int ip = cntP, inn = cntN;
    for (int off = 1; off < 64; off <<= 1) {
        int vp = __shfl_up(ip, off), vn = __shfl_up(inn, off);
        if (lane >= off) { ip += vp; inn += vn; }
    }
    if (lane == 63) { swP[wave] = ip; swN[wave] = inn; }
    __syncthreads();
    int bP = 0, bN = 0;
    for (int w = 0; w < wave; ++w) { bP += swP[w]; bN += swN[w]; }
    int pP = posBase[b * NBA + blockIdx.x] + bP + ip - cntP;
    int pN = negBase[b * NBA + blockIdx.x] + bN + inn - cntN;

    int npos = min(totPos[b], RPN_BATCH / 2);
    int negQ = RPN_BATCH - npos;

    float bce = 0.f, regv = 0.f;
#pragma unroll
    for (int j = 0; j < 4; ++j) {
        int i = gbase + j;
        if (i >= N_) break;
        if (lab[j] == 1) {
            int r = pP++;
            if (r < RPN_BATCH / 2) {
                float l = rpn_scores[(size_t)b * N_ + i];
                bce += fmaxf(l, 0.f) - l + log1pf(expf(-fabsf(l)));
                float4 A = ((const float4*)anchors)[i];
                float areaA = (A.z - A.x) * (A.w - A.y);
                float best = -1.f; int am = 0;
                for (int g = 0; g < G_; ++g) {
                    float iou = iou_one(A.x, A.y, A.z, A.w, areaA,
                                        sg[g * 4], sg[g * 4 + 1], sg[g * 4 + 2], sg[g * 4 + 3]);
                    if (iou > best) { best = iou; am = g; }
                }
                float t0 = sg[am * 4], t1 = sg[am * 4 + 1], t2 = sg[am * 4 + 2], t3 = sg[am * 4 + 3];
                float wa = A.z - A.x, ha = A.w - A.y;
                float xa = A.x + 0.5f * wa, ya = A.y + 0.5f * ha;
                float wt = t2 - t0, ht = t3 - t1;
                float xt = t0 + 0.5f * wt, yt = t1 + 0.5f * ht;
                float4 D = ((const float4*)rpn_deltas)[(size_t)b * N_ + i];
                regv += smooth_l1(D.x - (xt - xa) / wa) + smooth_l1(D.y - (yt - ya) / ha) +
                        smooth_l1(D.z - logf(wt / wa + 1e-6f)) + smooth_l1(D.w - logf(ht / ha + 1e-6f));
            }
        } else if (lab[j] == 0) {
            int r = pN++;
            if (r < negQ) {
                float l = rpn_scores[(size_t)b * N_ + i];
                bce += fmaxf(l, 0.f) + log1pf(expf(-fabsf(l)));
            }
        }
    }
    for (int m = 32; m >= 1; m >>= 1) { bce += __shfl_xor(bce, m); regv += __shfl_xor(regv, m); }
    if (lane == 0) { sred[wave] = bce; sred[4 + wave] = regv; }
    __syncthreads();
    if (tid == 0) {
        float sb = sred[0] + sred[1] + sred[2] + sred[3];
        float sr = sred[4] + sred[5] + sred[6] + sred[7];
        if (sb != 0.f) atomicAdd(&sums[b], sb);       // clsSum
        if (sr != 0.f) atomicAdd(&sums[4 + b], sr);   // regSum
    }
}

// Kernel 5: detection loss + RPN epilogue per batch.
__global__ void __launch_bounds__(128) det_final(
        const float* __restrict__ cls_scores, const float* __restrict__ bbox_deltas,
        const float* __restrict__ proposals, const float* __restrict__ gt_boxes,
        const int* __restrict__ gt_labels, const int* __restrict__ totPos,
        const int* __restrict__ totNeg, const float* __restrict__ sums,
        float* __restrict__ out) {
    int b = blockIdx.x, tid = threadIdx.x;
    __shared__ float sgt[G_ * 4];
    __shared__ int sgl[G_];
    __shared__ short sassign[P_];
    __shared__ unsigned char sargm[P_];
    __shared__ int scnt[128];
    __shared__ int ssamp[ROI_BATCH];
    __shared__ float rc[2], rr[2];
    __shared__ int rp[2];
    if (tid < G_ * 4) sgt[tid] = gt_boxes[b * G_ * 4 + tid];
    if (tid < G_) sgl[tid] = gt_labels[b * G_ + tid];
    __syncthreads();

    for (int p = tid; p < P_; p += 128) {
        const float* pr = proposals + ((size_t)b * P_ + p) * 4;
        float a0 = pr[0], a1 = pr[1], a2 = pr[2], a3 = pr[3];
        float areaA = (a2 - a0) * (a3 - a1);
        float best = -1.f; int am = 0;
        for (int g = 0; g < G_; ++g) {
            float iou = iou_one(a0, a1, a2, a3, areaA,
                                sgt[g * 4], sgt[g * 4 + 1], sgt[g * 4 + 2], sgt[g * 4 + 3]);
            if (iou > best) { best = iou; am = g; }
        }
        sassign[p] = (best >= 0.5f) ? (short)sgl[am] : (short)0;
        sargm[p] = (unsigned char)am;
    }
    __syncthreads();

    const int CH = 8;
    int c0 = tid * CH;
    int cnt = 0;
    for (int k = 0; k < CH; ++k) {
        int p = c0 + k;
        if (p < P_ && sassign[p] > 0) cnt++;
    }
    scnt[tid] = cnt;
    __syncthreads();
    for (int off = 1; off < 128; off <<= 1) {
        int v = (tid >= off) ? scnt[tid - off] : 0;
        __syncthreads();
        scnt[tid] += v;
        __syncthreads();
    }
    int npos_total = scnt[127];
    int npos_kept = min(npos_total, ROI_BATCH / 4);
    int nneg_total = P_ - npos_total;
    int prefix = scnt[tid] - cnt;
    for (int k = 0; k < CH; ++k) {
        int p = c0 + k;
        if (p >= P_) break;
        int slot;
        if (sassign[p] > 0) {
            if (prefix < ROI_BATCH / 4) slot = prefix;
            else slot = npos_kept + nneg_total + (prefix - ROI_BATCH / 4);
            prefix++;
        } else {
            slot = npos_kept + (p - prefix);
        }
        if (slot < ROI_BATCH) ssamp[slot] = p;
    }
    __syncthreads();

    float clsv = 0.f, regv = 0.f;
    int posc = 0;
    if (tid < ROI_BATCH) {
        int s = ssamp[tid];
        int t = sassign[s];
        const float* row = cls_scores + ((size_t)b * P_ + s) * C_;
        float m = -INFINITY;
        for (int c = 0; c < C_; ++c) m = fmaxf(m, row[c]);
        float se = 0.f;
        for (int c = 0; c < C_; ++c) se += expf(row[c] - m);
        clsv = -(row[t] - m - logf(se));
        if (t > 0) {
            posc = 1;
            int g = sargm[s];
            const float* pr = proposals + ((size_t)b * P_ + s) * 4;
            float a0 = pr[0], a1 = pr[1], a2 = pr[2], a3 = pr[3];
            float t0 = sgt[g * 4], t1 = sgt[g * 4 + 1], t2 = sgt[g * 4 + 2], t3 = sgt[g * 4 + 3];
            float wa = a2 - a0, ha = a3 - a1;
            float xa = a0 + 0.5f * wa, ya = a1 + 0.5f * ha;
            float wt = t2 - t0, ht = t3 - t1;
            float xt = t0 + 0.5f * wt, yt = t1 + 0.5f * ht;
            const float* pd = bbox_deltas + ((size_t)b * P_ + s) * (4 * C_) + 4 * t;
            regv = smooth_l1(pd[0] - (xt - xa) / wa) + smooth_l1(pd[1] - (yt - ya) / ha) +
                   smooth_l1(pd[2] - logf(wt / wa + 1e-6f)) + smooth_l1(pd[3] - logf(ht / ha + 1e-6f));
        }
    }
    int lane = tid & 63, wave = tid >> 6;
    for (int m = 32; m >= 1; m >>= 1) {
        clsv += __shfl_xor(clsv, m);
        regv += __shfl_xor(regv, m);
        posc += __shfl_xor(posc, m);
    }
    if (lane == 0) { rc[wave] = clsv; rr[wave] = regv; rp[wave] = posc; }
    __syncthreads();
    if (tid == 0) {
        float cls = (rc[0] + rc[1]) / (float)ROI_BATCH;
        int np = rp[0] + rp[1];
        float reg = (np > 0) ? (rr[0] + rr[1]) / fmaxf((float)np * 4.f, 1.f) : 0.f;
        // RPN epilogue for this batch
        int rnp = min(totPos[b], RPN_BATCH / 2);
        int kneg = min(totNeg[b], RPN_BATCH - rnp);
        float rdenom = fmaxf((float)(rnp + kneg), 1.f);
        float rcls = sums[b] / rdenom;
        float rreg = (rnp > 0) ? sums[4 + b] / fmaxf((float)rnp * 4.f, 1.f) : 0.f;
        atomicAdd(out, cls + reg + rcls + rreg);
    }
}

extern "C" void kernel_launch(void* const* d_in, const int* in_sizes, int n_in,
                              void* d_out, int out_size, void* d_ws, size_t ws_size,
                              hipStream_t stream) {
    const float* rpn_scores  = (const float*)d_in[0];
    const float* rpn_deltas  = (const float*)d_in[1];
    const float* cls_scores  = (const float*)d_in[2];
    const float* bbox_deltas = (const float*)d_in[3];
    const float* anchors     = (const float*)d_in[4];
    const float* proposals   = (const float*)d_in[5];
    const float* gt_boxes    = (const float*)d_in[6];
    const int*   gt_labels   = (const int*)d_in[7];
    float* out = (float*)d_out;

    char* ws = (char*)d_ws;
    size_t off = 0;
    auto alloc = [&](size_t bytes) -> char* {
        size_t o = (off + 255) & ~(size_t)255;
        off = o + bytes;
        return ws + o;
    };
    int8_t* labels = (int8_t*)alloc((size_t)B_ * N_);
    unsigned long long* blockBest = (unsigned long long*)alloc((size_t)B_ * G_ * NBA * 8);
    int* posCnt = (int*)alloc((size_t)B_ * NBA * 4);
    int* negCnt = (int*)alloc((size_t)B_ * NBA * 4);
    int* totPos = (int*)alloc(B_ * 4);
    int* totNeg = (int*)alloc(B_ * 4);
    float* sums = (float*)alloc(8 * 4);    // clsSum[4] | regSum[4]

    hipMemsetAsync(sums, 0, 8 * sizeof(float), stream);
    hipMemsetAsync(out, 0, (size_t)out_size * sizeof(float), stream);

    rpn_assign<<<dim3(NBA, B_), 256, 0, stream>>>(anchors, gt_boxes, labels,
                                                  posCnt, negCnt, blockBest);
    rpn_promote<<<B_, 256, 0, stream>>>(blockBest, labels, posCnt, negCnt);
    rpn_scan<<<B_, 256, 0, stream>>>(posCnt, negCnt, totPos, totNeg);
    rpn_sample<<<dim3(NBA, B_), 256, 0, stream>>>(labels, rpn_scores, rpn_deltas,
                                                  anchors, gt_boxes, posCnt, negCnt,
                                                  totPos, sums);
    det_final<<<B_, 128, 0, stream>>>(cls_scores, bbox_deltas, proposals, gt_boxes,
                                      gt_labels, totPos, totNeg, sums, out);
}

// Round 4
// 161.829 us; speedup vs baseline: 1.7398x; 1.1725x over previous
//
#include <hip/hip_runtime.h>
#include <math.h>
#include <stdint.h>

#define B_ 4
#define N_ 250000
#define P_ 1000
#define G_ 32
#define C_ 81
#define RPN_BATCH 256
#define ROI_BATCH 128

#define ABLK 1024                                   // anchors per block
#define NBA ((N_ + ABLK - 1) / ABLK)                // 245

__device__ __forceinline__ float iou_one(float a0, float a1, float a2, float a3,
                                         float areaA,
                                         float b0, float b1, float b2, float b3) {
    float ltx = fmaxf(a0, b0), lty = fmaxf(a1, b1);
    float rbx = fminf(a2, b2), rby = fminf(a3, b3);
    float w = fmaxf(rbx - ltx, 0.f), h = fmaxf(rby - lty, 0.f);
    float inter = w * h;
    float areaB = (b2 - b0) * (b3 - b1);
    return inter / (areaA + areaB - inter + 1e-6f);
}

__device__ __forceinline__ unsigned long long shfl_xor_u64(unsigned long long v, int m) {
    unsigned lo = (unsigned)v, hi = (unsigned)(v >> 32);
    lo = __shfl_xor(lo, m);
    hi = __shfl_xor(hi, m);
    return ((unsigned long long)hi << 32) | lo;
}

__device__ __forceinline__ float smooth_l1(float x) {
    float ax = fabsf(x);
    return (ax < 1.f) ? 0.5f * x * x : ax - 0.5f;
}

// Kernel 1: labels + per-block pos/neg counts + per-(block,gt) best anchor.
// Wave w handles gts [8w,8w+8) for all ABLK anchors; no division in hot loop.
// Block (0,0) also zero-inits sums[] and out[] (replaces two memset dispatches).
__global__ void __launch_bounds__(256, 4) rpn_assign(
        const float* __restrict__ anchors, const float* __restrict__ gt_boxes,
        int8_t* __restrict__ labels, int* __restrict__ posCnt, int* __restrict__ negCnt,
        unsigned long long* __restrict__ blockBest,
        float* __restrict__ sums, float* __restrict__ out, int out_size) {
    __shared__ float4 sA[ABLK];                 // 16 KB
    __shared__ float sArea[ABLK];               // 4 KB
    __shared__ float sGt[G_ * 5];
    __shared__ unsigned char sPart[4][ABLK];    // 4 KB
    __shared__ int sCnt[8];

    int b = blockIdx.y, tid = threadIdx.x;
    int base = blockIdx.x * ABLK;

    if (blockIdx.x == 0 && b == 0) {
        if (tid < 8) sums[tid] = 0.f;
        for (int i = tid; i < out_size; i += 256) out[i] = 0.f;
    }

    for (int t = tid; t < ABLK; t += 256) {
        int ai = base + t;
        float4 v = make_float4(0.f, 0.f, 0.f, 0.f);
        if (ai < N_) v = ((const float4*)anchors)[ai];
        sA[t] = v;
        sArea[t] = (v.z - v.x) * (v.w - v.y);
    }
    if (tid < G_) {
        float4 g = ((const float4*)gt_boxes)[b * G_ + tid];
        sGt[tid * 5 + 0] = g.x; sGt[tid * 5 + 1] = g.y;
        sGt[tid * 5 + 2] = g.z; sGt[tid * 5 + 3] = g.w;
        sGt[tid * 5 + 4] = (g.z - g.x) * (g.w - g.y) + 1e-6f;
    }
    __syncthreads();

    int lane = tid & 63, wave = tid >> 6;

    float g0[8], g1[8], g2[8], g3[8], gae[8];
#pragma unroll
    for (int j = 0; j < 8; ++j) {
        int gg = wave * 8 + j;
        g0[j] = sGt[gg * 5 + 0]; g1[j] = sGt[gg * 5 + 1];
        g2[j] = sGt[gg * 5 + 2]; g3[j] = sGt[gg * 5 + 3];
        gae[j] = sGt[gg * 5 + 4];
    }

    float bi[8], bd[8]; int bx[8];
#pragma unroll
    for (int j = 0; j < 8; ++j) { bi[j] = 0.f; bd[j] = 1.f; bx[j] = 0; }

    for (int k = 0; k < ABLK / 64; ++k) {
        int a = k * 64 + lane;
        float4 A = sA[a];
        float areaA = sArea[a];
        int gidx = base + a;
        float acc03 = 1e30f, acc07 = 1e30f;
#pragma unroll
        for (int j = 0; j < 8; ++j) {
            float ltx = fmaxf(A.x, g0[j]), lty = fmaxf(A.y, g1[j]);
            float rbx = fminf(A.z, g2[j]), rby = fminf(A.w, g3[j]);
            float w = fmaxf(rbx - ltx, 0.f), h = fmaxf(rby - lty, 0.f);
            float inter = w * h;
            float d = (areaA + gae[j]) - inter;
            acc03 = fminf(acc03, fmaf(0.3f, d, -inter)); // >0 => iou<0.3
            acc07 = fminf(acc07, fmaf(0.7f, d, -inter)); // <0 => iou>0.7
            float p1 = inter * bd[j], p2 = bi[j] * d;
            if (p1 > p2) { bi[j] = inter; bd[j] = d; bx[j] = gidx; }
        }
        sPart[wave][a] = (unsigned char)(((acc07 < 0.f) ? 2 : 0) | ((acc03 > 0.f) ? 1 : 0));
    }

#pragma unroll
    for (int j = 0; j < 8; ++j) {
        float i_ = bi[j], d_ = bd[j]; int x_ = bx[j];
        for (int m = 32; m >= 1; m >>= 1) {
            float oi = __shfl_xor(i_, m), od = __shfl_xor(d_, m);
            int ox = __shfl_xor(x_, m);
            float pa = oi * d_, pb = i_ * od;
            bool take = (pa > pb) || (pa == pb && ox < x_);
            if (take) { i_ = oi; d_ = od; x_ = ox; }
        }
        if (lane == 0) {
            float iou = i_ / d_;
            unsigned long long pk =
                (((unsigned long long)__float_as_uint(iou)) << 32) |
                (unsigned)(0xFFFFFFFFu - (unsigned)x_);
            blockBest[((size_t)b * G_ + wave * 8 + j) * NBA + blockIdx.x] = pk;
        }
    }
    __syncthreads();

    unsigned u0 = ((const unsigned*)&sPart[0][0])[tid];
    unsigned u1 = ((const unsigned*)&sPart[1][0])[tid];
    unsigned u2 = ((const unsigned*)&sPart[2][0])[tid];
    unsigned u3 = ((const unsigned*)&sPart[3][0])[tid];
    unsigned andb = u0 & u1 & u2 & u3;
    unsigned orb  = u0 | u1 | u2 | u3;
    int gbase = base + tid * 4;
    unsigned outw = 0; int cp = 0, cn = 0;
#pragma unroll
    for (int j = 0; j < 4; ++j) {
        int above = (orb >> (8 * j + 1)) & 1;
        int below = (andb >> (8 * j)) & 1;
        int lab = above ? 1 : (below ? 0 : -1);
        if (gbase + j < N_) { cp += (lab == 1); cn += (lab == 0); }
        outw |= ((unsigned)(unsigned char)(char)lab) << (8 * j);
    }
    if (gbase < N_)
        ((unsigned*)labels)[(((size_t)b * N_ + base) >> 2) + tid] = outw;

    for (int m = 32; m >= 1; m >>= 1) { cp += __shfl_xor(cp, m); cn += __shfl_xor(cn, m); }
    if (lane == 0) { sCnt[wave] = cp; sCnt[4 + wave] = cn; }
    __syncthreads();
    if (tid == 0) {
        posCnt[b * NBA + blockIdx.x] = sCnt[0] + sCnt[1] + sCnt[2] + sCnt[3];
        negCnt[b * NBA + blockIdx.x] = sCnt[4] + sCnt[5] + sCnt[6] + sCnt[7];
    }
}

// Kernel 2: per-gt global winner, dedupe, promote label + adjust counts.
__global__ void __launch_bounds__(256) rpn_promote(
        const unsigned long long* __restrict__ blockBest, int8_t* __restrict__ labels,
        int* __restrict__ posCnt, int* __restrict__ negCnt) {
    int b = blockIdx.x, tid = threadIdx.x;
    int g = tid >> 3, sub = tid & 7;
    unsigned long long v = 0;
    for (int j = sub; j < NBA; j += 8) {
        unsigned long long x = blockBest[((size_t)b * G_ + g) * NBA + j];
        if (x > v) v = x;
    }
    for (int m = 4; m >= 1; m >>= 1) {
        unsigned long long o = shfl_xor_u64(v, m);
        if (o > v) v = o;
    }
    __shared__ unsigned wIdx[G_];
    if (sub == 0) wIdx[g] = 0xFFFFFFFFu - (unsigned)(v & 0xFFFFFFFFull);
    __syncthreads();
    if (tid < G_) {
        unsigned w = wIdx[tid];
        bool first = true;
        for (int j = 0; j < tid; ++j) if (wIdx[j] == w) first = false;
        if (first) {
            size_t li = (size_t)b * N_ + w;
            int8_t old = labels[li];
            labels[li] = 1;
            int blk = (int)(w / ABLK);
            if (old != 1) atomicAdd(&posCnt[b * NBA + blk], 1);
            if (old == 0) atomicAdd(&negCnt[b * NBA + blk], -1);
        }
    }
}

// Kernel 3: exclusive scan of per-block counts.
__global__ void __launch_bounds__(256) rpn_scan(
        int* __restrict__ posCnt, int* __restrict__ negCnt,
        int* __restrict__ totPos, int* __restrict__ totNeg) {
    int b = blockIdx.x, tid = threadIdx.x;
    __shared__ int sp[256], sn[256];
    int vp = (tid < NBA) ? posCnt[b * NBA + tid] : 0;
    int vn = (tid < NBA) ? negCnt[b * NBA + tid] : 0;
    sp[tid] = vp; sn[tid] = vn;
    __syncthreads();
    for (int off = 1; off < 256; off <<= 1) {
        int tp = 0, tn = 0;
        if (tid >= off) { tp = sp[tid - off]; tn = sn[tid - off]; }
        __syncthreads();
        sp[tid] += tp; sn[tid] += tn;
        __syncthreads();
    }
    if (tid < NBA) { posCnt[b * NBA + tid] = sp[tid] - vp; negCnt[b * NBA + tid] = sn[tid] - vn; }
    if (tid == 0) { totPos[b] = sp[255]; totNeg[b] = sn[255]; }
}

// Kernel 4: ranks -> kept samples; BCE sum; reg loss for kept positives.
__global__ void __launch_bounds__(256) rpn_sample(
        const int8_t* __restrict__ labels, const float* __restrict__ rpn_scores,
        const float* __restrict__ rpn_deltas, const float* __restrict__ anchors,
        const float* __restrict__ gt_boxes,
        const int* __restrict__ posBase, const int* __restrict__ negBase,
        const int* __restrict__ totPos, float* __restrict__ sums) {
    int b = blockIdx.y, tid = threadIdx.x;
    int base = blockIdx.x * ABLK;
    __shared__ float sg[G_ * 4];
    __shared__ int swP[4], swN[4];
    __shared__ float sred[8];
    if (tid < G_ * 4) sg[tid] = gt_boxes[b * G_ * 4 + tid];

    int gbase = base + tid * 4;
    unsigned word = 0xFFFFFFFFu;
    if (gbase < N_)
        word = ((const unsigned*)labels)[(((size_t)b * N_ + base) >> 2) + tid];
    int lab[4]; int cntP = 0, cntN = 0;
#pragma unroll
    for (int j = 0; j < 4; ++j) {
        lab[j] = (int)(char)((word >> (8 * j)) & 0xFF);
        cntP += (lab[j] == 1); cntN += (lab[j] == 0);
    }
    int lane = tid & 63, wave = tid >> 6;
    int ip = cntP, inn = cntN;
    for (int off = 1; off < 64; off <<= 1) {
        int vp = __shfl_up(ip, off), vn = __shfl_up(inn, off);
        if (lane >= off) { ip += vp; inn += vn; }
    }
    if (lane == 63) { swP[wave] = ip; swN[wave] = inn; }
    __syncthreads();
    int bP = 0, bN = 0;
    for (int w = 0; w < wave; ++w) { bP += swP[w]; bN += swN[w]; }
    int pP = posBase[b * NBA + blockIdx.x] + bP + ip - cntP;
    int pN = negBase[b * NBA + blockIdx.x] + bN + inn - cntN;

    int npos = min(totPos[b], RPN_BATCH / 2);
    int negQ = RPN_BATCH - npos;

    float bce = 0.f, regv = 0.f;
#pragma unroll
    for (int j = 0; j < 4; ++j) {
        int i = gbase + j;
        if (i >= N_) break;
        if (lab[j] == 1) {
            int r = pP++;
            if (r < RPN_BATCH / 2) {
                float l = rpn_scores[(size_t)b * N_ + i];
                bce += fmaxf(l, 0.f) - l + log1pf(expf(-fabsf(l)));
                float4 A = ((const float4*)anchors)[i];
                float areaA = (A.z - A.x) * (A.w - A.y);
                float best = -1.f; int am = 0;
                for (int g = 0; g < G_; ++g) {
                    float iou = iou_one(A.x, A.y, A.z, A.w, areaA,
                                        sg[g * 4], sg[g * 4 + 1], sg[g * 4 + 2], sg[g * 4 + 3]);
                    if (iou > best) { best = iou; am = g; }
                }
                float t0 = sg[am * 4], t1 = sg[am * 4 + 1], t2 = sg[am * 4 + 2], t3 = sg[am * 4 + 3];
                float wa = A.z - A.x, ha = A.w - A.y;
                float xa = A.x + 0.5f * wa, ya = A.y + 0.5f * ha;
                float wt = t2 - t0, ht = t3 - t1;
                float xt = t0 + 0.5f * wt, yt = t1 + 0.5f * ht;
                float4 D = ((const float4*)rpn_deltas)[(size_t)b * N_ + i];
                regv += smooth_l1(D.x - (xt - xa) / wa) + smooth_l1(D.y - (yt - ya) / ha) +
                        smooth_l1(D.z - logf(wt / wa + 1e-6f)) + smooth_l1(D.w - logf(ht / ha + 1e-6f));
            }
        } else if (lab[j] == 0) {
            int r = pN++;
            if (r < negQ) {
                float l = rpn_scores[(size_t)b * N_ + i];
                bce += fmaxf(l, 0.f) + log1pf(expf(-fabsf(l)));
            }
        }
    }
    for (int m = 32; m >= 1; m >>= 1) { bce += __shfl_xor(bce, m); regv += __shfl_xor(regv, m); }
    if (lane == 0) { sred[wave] = bce; sred[4 + wave] = regv; }
    __syncthreads();
    if (tid == 0) {
        float sb = sred[0] + sred[1] + sred[2] + sred[3];
        float sr = sred[4] + sred[5] + sred[6] + sred[7];
        if (sb != 0.f) atomicAdd(&sums[b], sb);
        if (sr != 0.f) atomicAdd(&sums[4 + b], sr);
    }
}

// Kernel 5: whole detection loss + per-batch epilogue, one 1024-thread block per batch.
// Phase 1: 1 proposal/thread assign. Phase 2: shfl-scan sampling. Phase 3: one
// wave per ROI softmax (lane l holds row[l], row[64+l]). Epilogue atomicAdds out.
__global__ void __launch_bounds__(1024) det_all(
        const float* __restrict__ cls_scores, const float* __restrict__ bbox_deltas,
        const float* __restrict__ proposals, const float* __restrict__ gt_boxes,
        const int* __restrict__ gt_labels, const int* __restrict__ totPos,
        const int* __restrict__ totNeg, const float* __restrict__ sums,
        float* __restrict__ out) {
    int b = blockIdx.x, tid = threadIdx.x;
    int lane = tid & 63, wave = tid >> 6;
    __shared__ float sgt[G_ * 4];
    __shared__ int sgl[G_];
    __shared__ short sassign[P_];
    __shared__ unsigned char sargm[P_];
    __shared__ int sw[16];
    __shared__ int ssamp[ROI_BATCH];
    __shared__ float cacc[16], racc[16];
    if (tid < G_ * 4) sgt[tid] = gt_boxes[b * G_ * 4 + tid];
    if (tid < G_) sgl[tid] = gt_labels[b * G_ + tid];
    __syncthreads();

    // phase 1: assign
    int lab = 0;
    if (tid < P_) {
        float4 A = ((const float4*)proposals)[b * P_ + tid];
        float areaA = (A.z - A.x) * (A.w - A.y);
        float best = -1.f; int am = 0;
#pragma unroll 8
        for (int g = 0; g < G_; ++g) {
            float iou = iou_one(A.x, A.y, A.z, A.w, areaA,
                                sgt[g * 4], sgt[g * 4 + 1], sgt[g * 4 + 2], sgt[g * 4 + 3]);
            if (iou > best) { best = iou; am = g; }
        }
        lab = (best >= 0.5f) ? sgl[am] : 0;
        sassign[tid] = (short)lab;
        sargm[tid] = (unsigned char)am;
    }

    // phase 2: sampling ranks
    int cnt = (tid < P_ && lab > 0) ? 1 : 0;
    int inc = cnt;
    for (int off = 1; off < 64; off <<= 1) {
        int v = __shfl_up(inc, off);
        if (lane >= off) inc += v;
    }
    if (lane == 63) sw[wave] = inc;
    __syncthreads();
    int basew = 0, total = 0;
    for (int w = 0; w < 16; ++w) { if (w < wave) basew += sw[w]; total += sw[w]; }
    int prefix = basew + inc - cnt;                 // positives strictly before tid
    int npos_kept = min(total, ROI_BATCH / 4);
    int nneg_total = P_ - total;
    if (tid < P_) {
        int slot;
        if (lab > 0)
            slot = (prefix < ROI_BATCH / 4) ? prefix
                 : npos_kept + nneg_total + (prefix - ROI_BATCH / 4);
        else
            slot = npos_kept + (tid - prefix);
        if (slot < ROI_BATCH) ssamp[slot] = tid;
    }
    int np_det = npos_kept + max(0, ROI_BATCH - npos_kept - nneg_total);
    __syncthreads();

    // phase 3: one wave per 8 ROIs
    float clsv = 0.f, regv = 0.f;
    for (int k = 0; k < 8; ++k) {
        int r = wave * 8 + k;
        int s = ssamp[r];
        int t = sassign[s];
        const float* row = cls_scores + ((size_t)(b * P_ + s)) * C_;
        float v1 = row[lane];
        float v2 = (lane < C_ - 64) ? row[64 + lane] : -INFINITY;
        float m = fmaxf(v1, v2);
        for (int mm = 32; mm >= 1; mm >>= 1) m = fmaxf(m, __shfl_xor(m, mm));
        float se = expf(v1 - m) + ((lane < C_ - 64) ? expf(v2 - m) : 0.f);
        for (int mm = 32; mm >= 1; mm >>= 1) se += __shfl_xor(se, mm);
        if (lane == 0) {
            clsv += -(row[t] - m - logf(se));
            if (t > 0) {
                int g = sargm[s];
                float4 A = ((const float4*)proposals)[b * P_ + s];
                float t0 = sgt[g * 4], t1 = sgt[g * 4 + 1];
                float t2 = sgt[g * 4 + 2], t3 = sgt[g * 4 + 3];
                float wa = A.z - A.x, ha = A.w - A.y;
                float xa = A.x + 0.5f * wa, ya = A.y + 0.5f * ha;
                float wt = t2 - t0, ht = t3 - t1;
                float xt = t0 + 0.5f * wt, yt = t1 + 0.5f * ht;
                const float4 pd = *(const float4*)(bbox_deltas +
                        ((size_t)(b * P_ + s)) * (4 * C_) + 4 * t);
                regv += smooth_l1(pd.x - (xt - xa) / wa) + smooth_l1(pd.y - (yt - ya) / ha) +
                        smooth_l1(pd.z - logf(wt / wa + 1e-6f)) + smooth_l1(pd.w - logf(ht / ha + 1e-6f));
            }
        }
    }
    if (lane == 0) { cacc[wave] = clsv; racc[wave] = regv; }
    __syncthreads();
    if (tid == 0) {
        float cs = 0.f, rs = 0.f;
        for (int w = 0; w < 16; ++w) { cs += cacc[w]; rs += racc[w]; }
        float cls = cs / (float)ROI_BATCH;
        float reg = (np_det > 0) ? rs / fmaxf((float)np_det * 4.f, 1.f) : 0.f;
        int rnp = min(totPos[b], RPN_BATCH / 2);
        int kneg = min(totNeg[b], RPN_BATCH - rnp);
        float rcls = sums[b] / fmaxf((float)(rnp + kneg), 1.f);
        float rreg = (rnp > 0) ? sums[4 + b] / fmaxf((float)rnp * 4.f, 1.f) : 0.f;
        atomicAdd(out, cls + reg + rcls + rreg);
    }
}

extern "C" void kernel_launch(void* const* d_in, const int* in_sizes, int n_in,
                              void* d_out, int out_size, void* d_ws, size_t ws_size,
                              hipStream_t stream) {
    const float* rpn_scores  = (const float*)d_in[0];
    const float* rpn_deltas  = (const float*)d_in[1];
    const float* cls_scores  = (const float*)d_in[2];
    const float* bbox_deltas = (const float*)d_in[3];
    const float* anchors     = (const float*)d_in[4];
    const float* proposals   = (const float*)d_in[5];
    const float* gt_boxes    = (const float*)d_in[6];
    const int*   gt_labels   = (const int*)d_in[7];
    float* out = (float*)d_out;

    char* ws = (char*)d_ws;
    size_t off = 0;
    auto alloc = [&](size_t bytes) -> char* {
        size_t o = (off + 255) & ~(size_t)255;
        off = o + bytes;
        return ws + o;
    };
    int8_t* labels = (int8_t*)alloc((size_t)B_ * N_);
    unsigned long long* blockBest = (unsigned long long*)alloc((size_t)B_ * G_ * NBA * 8);
    int* posCnt = (int*)alloc((size_t)B_ * NBA * 4);
    int* negCnt = (int*)alloc((size_t)B_ * NBA * 4);
    int* totPos = (int*)alloc(B_ * 4);
    int* totNeg = (int*)alloc(B_ * 4);
    float* sums = (float*)alloc(8 * 4);    // clsSum[4] | regSum[4]

    rpn_assign<<<dim3(NBA, B_), 256, 0, stream>>>(anchors, gt_boxes, labels,
                                                  posCnt, negCnt, blockBest,
                                                  sums, out, out_size);
    rpn_promote<<<B_, 256, 0, stream>>>(blockBest, labels, posCnt, negCnt);
    rpn_scan<<<B_, 256, 0, stream>>>(posCnt, negCnt, totPos, totNeg);
    rpn_sample<<<dim3(NBA, B_), 256, 0, stream>>>(labels, rpn_scores, rpn_deltas,
                                                  anchors, gt_boxes, posCnt, negCnt,
                                                  totPos, sums);
    det_all<<<B_, 1024, 0, stream>>>(cls_scores, bbox_deltas, proposals, gt_boxes,
                                     gt_labels, totPos, totNeg, sums, out);
}